// Round 7
// baseline (198.188 us; speedup 1.0000x reference)
//
#include <hip/hip_runtime.h>

// MultiHeadAttention: B=2, N=2048, C=768, H=12, DH=64. fp32 in/out, bf16 MFMA compute.
// R12 = R11 with the GEMM pipeline FIXED per T4 (counted vmcnt, never drain-0):
//  - ring-3 LDS buffers (48KB), stage issued 2 tiles ahead via global_load_lds;
//  - per step: sched_barrier; s_waitcnt vmcnt(4); s_barrier; sched_barrier;
//    STAGE(s+2); COMPUTE(s).  The barrier no longer drains the in-flight next
//    stage -> loads get 2 compute phases (~400+cy) to land (R11's __syncthreads
//    drained vmcnt(0) after ONE short BK=32 phase -> degenerated serial).
//  - tail peeled with vmcnt(4)/(4)/(0).  Numerics identical (same MFMA order).
// attn / converts / epilogues identical to R10/R11.

typedef __bf16 bf16_t;
typedef __bf16 bf16x8 __attribute__((ext_vector_type(8)));
typedef __bf16 bf16x4 __attribute__((ext_vector_type(4)));
typedef short  short4_t __attribute__((ext_vector_type(4)));
typedef float  floatx4 __attribute__((ext_vector_type(4)));

#define MFMA32(a, b, c) __builtin_amdgcn_mfma_f32_16x16x32_bf16(a, b, c, 0, 0, 0)
#define MFMA16(a, b, c) __builtin_amdgcn_mfma_f32_16x16x16bf16_1k(a, b, c, 0, 0, 0)

__device__ __forceinline__ void gload16(const bf16_t* g, bf16_t* l) {
  __builtin_amdgcn_global_load_lds(
      (__attribute__((address_space(1))) void*)g,
      (__attribute__((address_space(3))) void*)l, 16, 0, 0);
}

// ---------------------------------------------------------------- converts --
__global__ __launch_bounds__(256) void cvt_x_kernel(const float* __restrict__ x,
                                                    bf16_t* __restrict__ xb) {
  int i = blockIdx.x * 256 + threadIdx.x;
  floatx4 v = ((const floatx4*)x)[i];
  bf16x4 o;
  o[0] = (bf16_t)v[0]; o[1] = (bf16_t)v[1]; o[2] = (bf16_t)v[2]; o[3] = (bf16_t)v[3];
  ((bf16x4*)xb)[i] = o;
}

// W [in=768][out=768] fp32 -> WT [out][in] bf16; blockIdx.z picks which matrix.
__global__ __launch_bounds__(256) void cvt_wt_kernel(
    const float* __restrict__ W0, const float* __restrict__ W1,
    const float* __restrict__ W2, const float* __restrict__ W3,
    bf16_t* __restrict__ T0, bf16_t* __restrict__ T1,
    bf16_t* __restrict__ T2, bf16_t* __restrict__ T3) {
  const int z = blockIdx.z;
  const float* W = (z == 0) ? W0 : (z == 1) ? W1 : (z == 2) ? W2 : W3;
  bf16_t* WT = (z == 0) ? T0 : (z == 1) ? T1 : (z == 2) ? T2 : T3;
  __shared__ bf16_t T[64][65];
  const int c = threadIdx.x & 63, r0 = threadIdx.x >> 6;
  const int i0 = blockIdx.y * 64, o0 = blockIdx.x * 64;
#pragma unroll
  for (int p = 0; p < 16; ++p) {
    int r = p * 4 + r0;
    T[r][c] = (bf16_t)W[(i0 + r) * 768 + o0 + c];
  }
  __syncthreads();
#pragma unroll
  for (int p = 0; p < 16; ++p) {
    int r = p * 4 + r0;
    WT[(o0 + r) * 768 + i0 + c] = T[c][r];
  }
}

// ------------------------------------------------------------------- GEMMs --
// Fragment-order layouts (per bh = b*12+h, per 128-key tile kt):
//  K: elem(key,d) -> kt*8192 + ((nk*2+kk)*64 + quad*16 + l15)*8 + j
//     nk=key128>>4, l15=key128&15, kk=d>>5, quad=(d>>3)&3, j=d&7
//  V: elem(key,d) -> kt*8192 + ((nk*4+nd)*64 + vq*16 + vl15)*4 + j
//     nk=key128>>4, vq=(key128>>2)&3, j=key128&3, nd=d>>4, vl15=d&15

// K-loop pipeline (both GEMMs): ring-3 bufs, stage 2 ahead, counted vmcnt.
//  step s: [sched][vmcnt(4): own tile-s loads done][s_barrier: everyone's done]
//          [sched][STAGE(s+2) -> buf (s+2)%3 == (s-1)%3, readers passed barrier]
//          [COMPUTE(s)]
#define GSTEP(WAIT, SBUF, CBUF, S)                             \
  {                                                            \
    __builtin_amdgcn_sched_barrier(0);                         \
    asm volatile("s_waitcnt vmcnt(" #WAIT ")" ::: "memory");   \
    __builtin_amdgcn_s_barrier();                              \
    __builtin_amdgcn_sched_barrier(0);                         \
    if ((S) + 2 < 24) STAGE(SBUF, ((S) + 2) * 32);             \
    COMPUTE(CBUF);                                             \
  }

// Fused QKV, M = output channels (768), N = tokens (4096).
__global__ __launch_bounds__(256) void gemm_qkv(
    const bf16_t* __restrict__ Xb, const bf16_t* __restrict__ WqT,
    const bf16_t* __restrict__ WkT, const bf16_t* __restrict__ WvT,
    const float* __restrict__ bq, const float* __restrict__ bk,
    const float* __restrict__ bv, bf16_t* __restrict__ qw,
    bf16_t* __restrict__ kw, bf16_t* __restrict__ vtw) {
  __shared__ __align__(16) bf16_t Al[3][4096];  // [buf][128 rows x 32 cols]
  __shared__ __align__(16) bf16_t Bl[3][4096];
  const int z = blockIdx.z;
  const bf16_t* Wt = (z == 0) ? WqT : (z == 1) ? WkT : WvT;
  const float* bias = (z == 0) ? bq : (z == 1) ? bk : bv;
  const float oscale = (z == 0) ? 0.18033688011112042f : 1.0f;  // 0.125*log2(e)

  const int tid = threadIdx.x, lane = tid & 63, w = tid >> 6;
  const int wr = w >> 1, wc = w & 1;
  const int l15 = lane & 15, quad = lane >> 4;
  const int m0 = blockIdx.y * 128, n0 = blockIdx.x * 128;

  // staging: wave w covers rows [w*32, w*32+32): per call 16 rows, lane ->
  // (row w*32+p*16+(lane>>2), col (lane&3)*8); LDS dest = lane*16B (linear).
  const int srow = w * 32 + (lane >> 2);
  const int scol = (lane & 3) * 8;
  const bf16_t* gA = &Wt[(m0 + srow) * 768 + scol];
  const bf16_t* gB = &Xb[(n0 + srow) * 768 + scol];
  const int ldst = w * 1024 + lane * 8;

  floatx4 acc[4][4] = {};

#define STAGE(B, KS)                                   \
  {                                                    \
    gload16(gA + (KS), &Al[B][ldst]);                  \
    gload16(gA + (KS) + 16 * 768, &Al[B][ldst + 512]); \
    gload16(gB + (KS), &Bl[B][ldst]);                  \
    gload16(gB + (KS) + 16 * 768, &Bl[B][ldst + 512]); \
  }

#define COMPUTE(B)                                                          \
  {                                                                         \
    bf16x8 af[4], bfr[4];                                                   \
    _Pragma("unroll") for (int i = 0; i < 4; ++i) {                         \
      af[i]  = *(const bf16x8*)&Al[B][(wr * 64 + i * 16 + l15) * 32 + quad * 8]; \
      bfr[i] = *(const bf16x8*)&Bl[B][(wc * 64 + i * 16 + l15) * 32 + quad * 8]; \
    }                                                                       \
    _Pragma("unroll") for (int mi = 0; mi < 4; ++mi)                        \
        _Pragma("unroll") for (int ni = 0; ni < 4; ++ni)                    \
            acc[mi][ni] = MFMA32(af[mi], bfr[ni], acc[mi][ni]);             \
  }

  STAGE(0, 0);
  STAGE(1, 32);
  for (int sb = 0; sb < 21; sb += 3) {
    GSTEP(4, 2, 0, sb + 0);
    GSTEP(4, 0, 1, sb + 1);
    GSTEP(4, 1, 2, sb + 2);
  }
  GSTEP(4, 2, 0, 21);   // stages tile 23 into buf2
  GSTEP(4, 0, 1, 22);   // no stage (tile 24 doesn't exist)
  GSTEP(0, 1, 2, 23);   // final drain
#undef STAGE
#undef COMPUTE

  const int hh = (m0 + wr * 64) >> 6;  // head (64-aligned per wave-row)
#pragma unroll
  for (int mi = 0; mi < 4; ++mi) {
    const int d0 = mi * 16 + quad * 4;           // d within head, multiple of 4
    const int gm0 = m0 + wr * 64 + d0;
    float bv4[4];
#pragma unroll
    for (int r = 0; r < 4; ++r) bv4[r] = bias[gm0 + r];
#pragma unroll
    for (int ni = 0; ni < 4; ++ni) {
      const int gn = n0 + wc * 64 + ni * 16 + l15;
      const int bb = gn >> 11, tok = gn & 2047;
      const int bh = bb * 12 + hh;
      if (z == 0) {
        bf16x4 pk;
#pragma unroll
        for (int r = 0; r < 4; ++r)
          pk[r] = (bf16_t)((acc[mi][ni][r] + bv4[r]) * oscale);
        *(bf16x4*)&qw[bh * 131072 + tok * 64 + d0] = pk;
      } else if (z == 1) {
        const int kt2 = tok >> 7, k128 = tok & 127;
        const int nk = k128 >> 4, kl15 = k128 & 15;
        const int kk = d0 >> 5, kq = (d0 >> 3) & 3, j0 = d0 & 7;
        bf16x4 pk;
#pragma unroll
        for (int r = 0; r < 4; ++r)
          pk[r] = (bf16_t)(acc[mi][ni][r] + bv4[r]);
        *(bf16x4*)&kw[bh * 131072 + kt2 * 8192 +
                      ((nk * 2 + kk) * 64 + kq * 16 + kl15) * 8 + j0] = pk;
      } else {
        const int kt2 = tok >> 7, k128 = tok & 127;
        const int nk = k128 >> 4, vq = (k128 >> 2) & 3, j = k128 & 3;
        const int nd = d0 >> 4, vl0 = d0 & 15;
        const int base = bh * 131072 + kt2 * 8192 +
                         ((nk * 4 + nd) * 64 + vq * 16 + vl0) * 4 + j;
#pragma unroll
        for (int r = 0; r < 4; ++r)
          vtw[base + r * 4] = (bf16_t)(acc[mi][ni][r] + bv4[r]);
      }
    }
  }
}

// Output projection, M = channels: out fp32 [4096 tok][768 ch] via float4 stores.
__global__ __launch_bounds__(256) void gemm_proj(
    const bf16_t* __restrict__ Yb, const bf16_t* __restrict__ WpT,
    const float* __restrict__ bias, float* __restrict__ out) {
  __shared__ __align__(16) bf16_t Al[3][4096];
  __shared__ __align__(16) bf16_t Bl[3][4096];
  const int tid = threadIdx.x, lane = tid & 63, w = tid >> 6;
  const int wr = w >> 1, wc = w & 1;
  const int l15 = lane & 15, quad = lane >> 4;
  const int m0 = blockIdx.y * 128, n0 = blockIdx.x * 128;

  const int srow = w * 32 + (lane >> 2);
  const int scol = (lane & 3) * 8;
  const bf16_t* gA = &WpT[(m0 + srow) * 768 + scol];
  const bf16_t* gB = &Yb[(n0 + srow) * 768 + scol];
  const int ldst = w * 1024 + lane * 8;

  floatx4 acc[4][4] = {};

#define STAGE(B, KS)                                   \
  {                                                    \
    gload16(gA + (KS), &Al[B][ldst]);                  \
    gload16(gA + (KS) + 16 * 768, &Al[B][ldst + 512]); \
    gload16(gB + (KS), &Bl[B][ldst]);                  \
    gload16(gB + (KS) + 16 * 768, &Bl[B][ldst + 512]); \
  }

#define COMPUTE(B)                                                          \
  {                                                                         \
    bf16x8 af[4], bfr[4];                                                   \
    _Pragma("unroll") for (int i = 0; i < 4; ++i) {                         \
      af[i]  = *(const bf16x8*)&Al[B][(wr * 64 + i * 16 + l15) * 32 + quad * 8]; \
      bfr[i] = *(const bf16x8*)&Bl[B][(wc * 64 + i * 16 + l15) * 32 + quad * 8]; \
    }                                                                       \
    _Pragma("unroll") for (int mi = 0; mi < 4; ++mi)                        \
        _Pragma("unroll") for (int ni = 0; ni < 4; ++ni)                    \
            acc[mi][ni] = MFMA32(af[mi], bfr[ni], acc[mi][ni]);             \
  }

  STAGE(0, 0);
  STAGE(1, 32);
  for (int sb = 0; sb < 21; sb += 3) {
    GSTEP(4, 2, 0, sb + 0);
    GSTEP(4, 0, 1, sb + 1);
    GSTEP(4, 1, 2, sb + 2);
  }
  GSTEP(4, 2, 0, 21);
  GSTEP(4, 0, 1, 22);
  GSTEP(0, 1, 2, 23);
#undef STAGE
#undef COMPUTE

#pragma unroll
  for (int mi = 0; mi < 4; ++mi) {
    const int gm0 = m0 + wr * 64 + mi * 16 + quad * 4;
    floatx4 bv4;
#pragma unroll
    for (int r = 0; r < 4; ++r) bv4[r] = bias[gm0 + r];
#pragma unroll
    for (int ni = 0; ni < 4; ++ni) {
      const int gn = n0 + wc * 64 + ni * 16 + l15;
      floatx4 v = acc[mi][ni] + bv4;
      *(floatx4*)&out[gn * 768 + gm0] = v;
    }
  }
}

// --------------------------------------------------------------- attention --
// Block: one (b,h), 64 Q rows.  Wave w=(wk<<1)|wq: wq picks 32-q half, wk picks
// the 32-key half of each 64-key tile.  K/V in fragment order -> each 64-key
// subtile is a contiguous 8KB range; staging = linear global_load_lds copy
// (no VGPRs, no VALU).  Double-buffered: stage(next) overlaps compute(cur);
// one __syncthreads per tile (its vmcnt(0) drain hits loads issued a full
// compute-phase earlier).  XCD mapping: block i -> XCD i&7; XCD x owns bh in
// [3x,3x+3) (1.5MB K/V, L2-resident).  lsum on MFMA pipe (ones-trick).
__global__ __launch_bounds__(256, 4) void attn_kernel(
    const bf16_t* __restrict__ Q, const bf16_t* __restrict__ Kf,
    const bf16_t* __restrict__ Vf, bf16_t* __restrict__ Y) {
  // buf b at smem+b*8192: K [0,4096), V [4096,8192) (elements)
  __shared__ __align__(16) bf16_t smem[16384];
  __shared__ float Ls[2][2][2][16];             // [wq][wk][ni][q&15]
  float* Ox = (float*)smem;                     // exchange region (16 KB used)

  const int tid = threadIdx.x, lane = tid & 63, w = tid >> 6;
  const int wq = w & 1, wk = w >> 1;
  const int l15 = lane & 15, quad = lane >> 4;

  // XCD-aware mapping (perf-only heuristic; any mapping is correct).
  const int i = blockIdx.x;           // 0..767
  const int xcd = i & 7, j = i >> 3;  // j: 0..95
  const int bh = xcd * 3 + (j >> 5);
  const int q0 = (j & 31) * 64;

  const bf16_t* Qb = Q + bh * 131072;
  const bf16_t* Kg = Kf + bh * 131072 + tid * 8;  // per-thread staging base
  const bf16_t* Vg = Vf + bh * 131072 + tid * 8;

  // Q B-frags (x32): n=q over l15, k=dh over quad*8+j.  32 q per wave.
  bf16x8 qf[2][2];
#pragma unroll
  for (int ni = 0; ni < 2; ++ni)
#pragma unroll
    for (int kk = 0; kk < 2; ++kk)
      qf[ni][kk] = *(const bf16x8*)&Qb[(q0 + wq * 32 + ni * 16 + l15) * 64 +
                                       kk * 32 + quad * 8];

  floatx4 oacc[2][4] = {};   // [ni(q16)][nd(d16)] partial over this wave's keys
  floatx4 sacc[2] = {};      // row-sums via MFMA ones-trick
  const short4_t ones = {0x3F80, 0x3F80, 0x3F80, 0x3F80};  // bf16 1.0 x4

  // stage 64-key tile t (elements [t*4096, t*4096+4096) of K and of V) into buf b
  auto stage = [&](int b, int t) {
    const bf16_t* kg = Kg + t * 4096;
    const bf16_t* vg = Vg + t * 4096;
    bf16_t* kl = smem + b * 8192 + tid * 8;
    bf16_t* vl = smem + b * 8192 + 4096 + tid * 8;
    gload16(kg, kl);
    gload16(kg + 2048, kl + 2048);
    gload16(vg, vl);
    gload16(vg + 2048, vl + 2048);
  };

  auto compute = [&](int b) {
    const bf16_t* Kl = smem + b * 8192;
    const bf16_t* Vl = smem + b * 8192 + 4096;
    // S^T = K*Q^T for this wave's 32 keys x 32 q; P = exp2 packed to x16 A-frags.
    short4_t pk[2][2];
#pragma unroll
    for (int mt = 0; mt < 2; ++mt) {
      floatx4 s[2] = {};
#pragma unroll
      for (int kk = 0; kk < 2; ++kk) {
        bf16x8 kfr = *(const bf16x8*)&Kl[((wk * 2 + mt) * 2 + kk) * 512 + lane * 8];
#pragma unroll
        for (int ni = 0; ni < 2; ++ni)
          s[ni] = MFMA32(kfr, qf[ni][kk], s[ni]);
      }
#pragma unroll
      for (int ni = 0; ni < 2; ++ni) {
        bf16x4 ph;
#pragma unroll
        for (int r = 0; r < 4; ++r)
          ph[r] = (bf16_t)__builtin_amdgcn_exp2f(s[ni][r]);
        pk[mt][ni] = __builtin_bit_cast(short4_t, ph);
      }
    }
    // O += P*V; sacc += P*1 (row-sums on the MFMA pipe).
#pragma unroll
    for (int mt = 0; mt < 2; ++mt) {
#pragma unroll
      for (int nd = 0; nd < 4; ++nd) {
        bf16x4 vfr = *(const bf16x4*)&Vl[((wk * 2 + mt) * 4 + nd) * 256 + lane * 4];
        short4_t vs = __builtin_bit_cast(short4_t, vfr);
#pragma unroll
        for (int ni = 0; ni < 2; ++ni)
          oacc[ni][nd] = MFMA16(pk[mt][ni], vs, oacc[ni][nd]);
      }
#pragma unroll
      for (int ni = 0; ni < 2; ++ni)
        sacc[ni] = MFMA16(pk[mt][ni], ones, sacc[ni]);
    }
  };

  stage(0, 0);
  __syncthreads();                       // buf0 ready (vmcnt(0) drain + barrier)
  for (int t = 0; t < 32; t += 2) {
    stage(1, t + 1);                     // async into buf1 during compute(buf0)
    compute(0);
    __syncthreads();                     // buf1 ready; everyone done with buf0
    if (t + 2 < 32) stage(0, t + 2);     // async into buf0 during compute(buf1)
    compute(1);
    __syncthreads();                     // buf0 ready; everyone done with buf1
  }

  // sacc[ni][r] = this wave's lsum for q = ni*16 + quad*4 + r (same across l15).
  if (l15 == 0) {
#pragma unroll
    for (int ni = 0; ni < 2; ++ni)
#pragma unroll
      for (int r = 0; r < 4; ++r)
        Ls[wq][wk][ni][quad * 4 + r] = sacc[ni][r];
  }

  // Each wave writes its NON-owned d-half (fp32, b128, conflict-free),
  // then reads partner's partial for its owned half.
#pragma unroll
  for (int ni = 0; ni < 2; ++ni)
#pragma unroll
    for (int ndl = 0; ndl < 2; ++ndl) {
      const int nd = (1 - wk) * 2 + ndl;
      *(floatx4*)&Ox[((((wq * 2 + wk) * 2 + ni) * 2 + ndl) * 64 + lane) * 4] =
          oacc[ni][nd];
    }
  __syncthreads();

  const int bb = bh / 12, h = bh % 12;
#pragma unroll
  for (int ni = 0; ni < 2; ++ni) {
    float tot[4];
#pragma unroll
    for (int r = 0; r < 4; ++r)
      tot[r] = Ls[wq][0][ni][quad * 4 + r] + Ls[wq][1][ni][quad * 4 + r];
#pragma unroll
    for (int ndl = 0; ndl < 2; ++ndl) {
      const int nd = wk * 2 + ndl;
      floatx4 o = oacc[ni][nd];
      floatx4 other =
          *(floatx4*)&Ox[((((wq * 2 + (1 - wk)) * 2 + ni) * 2 + ndl) * 64 + lane) * 4];
      o += other;
#pragma unroll
      for (int r = 0; r < 4; ++r) {
        const int tok = q0 + wq * 32 + ni * 16 + quad * 4 + r;
        const int col = h * 64 + nd * 16 + l15;
        Y[(bb * 2048 + tok) * 768 + col] = (bf16_t)(o[r] / tot[r]);
      }
    }
  }
}

// ------------------------------------------------------------------ launch --
extern "C" void kernel_launch(void* const* d_in, const int* in_sizes, int n_in,
                              void* d_out, int out_size, void* d_ws, size_t ws_size,
                              hipStream_t stream) {
  const float* x  = (const float*)d_in[0];
  const float* Wq = (const float*)d_in[1];
  const float* bq = (const float*)d_in[2];
  const float* Wk = (const float*)d_in[3];
  const float* bk = (const float*)d_in[4];
  const float* Wv = (const float*)d_in[5];
  const float* bv = (const float*)d_in[6];
  const float* Wp = (const float*)d_in[7];
  const float* bp = (const float*)d_in[8];
  float* out = (float*)d_out;

  char* ws = (char*)d_ws;
  bf16_t* xb  = (bf16_t*)ws; ws += (size_t)4096 * 768 * 2;
  bf16_t* WqT = (bf16_t*)ws; ws += (size_t)768 * 768 * 2;
  bf16_t* WkT = (bf16_t*)ws; ws += (size_t)768 * 768 * 2;
  bf16_t* WvT = (bf16_t*)ws; ws += (size_t)768 * 768 * 2;
  bf16_t* WpT = (bf16_t*)ws; ws += (size_t)768 * 768 * 2;
  bf16_t* qw  = (bf16_t*)ws; ws += (size_t)24 * 2048 * 64 * 2;
  bf16_t* kw  = (bf16_t*)ws; ws += (size_t)24 * 2048 * 64 * 2;
  bf16_t* vtw = (bf16_t*)ws; ws += (size_t)24 * 2048 * 64 * 2;
  bf16_t* yw  = (bf16_t*)ws; ws += (size_t)4096 * 768 * 2;

  cvt_x_kernel<<<3072, 256, 0, stream>>>(x, xb);
  cvt_wt_kernel<<<dim3(12, 12, 4), 256, 0, stream>>>(Wq, Wk, Wv, Wp, WqT, WkT, WvT, WpT);

  gemm_qkv<<<dim3(32, 6, 3), 256, 0, stream>>>(xb, WqT, WkT, WvT, bq, bk, bv, qw, kw, vtw);
  attn_kernel<<<768, 256, 0, stream>>>(qw, kw, vtw, yw);
  gemm_proj<<<dim3(32, 6), 256, 0, stream>>>(yw, WpT, bp, out);
}

// Round 8
// 186.322 us; speedup vs baseline: 1.0637x; 1.0637x over previous
//
#include <hip/hip_runtime.h>

// MultiHeadAttention: B=2, N=2048, C=768, H=12, DH=64. fp32 in/out, bf16 MFMA compute.
// R13 = R10 (best verified total, 187.2us: R5 padded-LDS GEMMs + pipelined attn)
// + ONE change: cvt_x and cvt_wt merged into a single kernel (5 -> 4 launches).
// Cross-round evidence says the 130us residual beyond attn is substantially
// serial-launch overhead (GEMM structure changes of 2-3x ladder-magnitude move
// the total <6%), so we cut a launch instead of restructuring GEMMs again.
// R12's sched_barrier-pinned ring-3 GEMM regressed (m141 mode) and is reverted.

typedef __bf16 bf16_t;
typedef __bf16 bf16x8 __attribute__((ext_vector_type(8)));
typedef __bf16 bf16x4 __attribute__((ext_vector_type(4)));
typedef short  short4_t __attribute__((ext_vector_type(4)));
typedef float  floatx4 __attribute__((ext_vector_type(4)));

#define MFMA32(a, b, c) __builtin_amdgcn_mfma_f32_16x16x32_bf16(a, b, c, 0, 0, 0)
#define MFMA16(a, b, c) __builtin_amdgcn_mfma_f32_16x16x16bf16_1k(a, b, c, 0, 0, 0)

__device__ __forceinline__ void gload16(const bf16_t* g, bf16_t* l) {
  __builtin_amdgcn_global_load_lds(
      (__attribute__((address_space(1))) void*)g,
      (__attribute__((address_space(3))) void*)l, 16, 0, 0);
}

// ---------------------------------------------------------------- converts --
// One kernel, 1D grid 3648: blocks [0,3072) convert x fp32->bf16 (vectorized);
// blocks [3072,3648) transpose+convert the 4 weight matrices (64x64 LDS tiles).
__global__ __launch_bounds__(256) void cvt_all_kernel(
    const float* __restrict__ x, const float* __restrict__ W0,
    const float* __restrict__ W1, const float* __restrict__ W2,
    const float* __restrict__ W3, bf16_t* __restrict__ xb,
    bf16_t* __restrict__ T0, bf16_t* __restrict__ T1,
    bf16_t* __restrict__ T2, bf16_t* __restrict__ T3) {
  __shared__ bf16_t T[64][65];
  const int id = blockIdx.x;
  if (id < 3072) {
    int i = id * 256 + threadIdx.x;
    floatx4 v = ((const floatx4*)x)[i];
    bf16x4 o;
    o[0] = (bf16_t)v[0]; o[1] = (bf16_t)v[1]; o[2] = (bf16_t)v[2]; o[3] = (bf16_t)v[3];
    ((bf16x4*)xb)[i] = o;
    return;
  }
  const int wid = id - 3072;              // 0..575
  const int z = wid / 144, rem = wid % 144;
  const int by = rem / 12, bx = rem % 12; // matches old grid (x=12, y=12, z=4)
  const float* W = (z == 0) ? W0 : (z == 1) ? W1 : (z == 2) ? W2 : W3;
  bf16_t* WT = (z == 0) ? T0 : (z == 1) ? T1 : (z == 2) ? T2 : T3;
  const int c = threadIdx.x & 63, r0 = threadIdx.x >> 6;
  const int i0 = by * 64, o0 = bx * 64;
#pragma unroll
  for (int p = 0; p < 16; ++p) {
    int r = p * 4 + r0;
    T[r][c] = (bf16_t)W[(i0 + r) * 768 + o0 + c];
  }
  __syncthreads();
#pragma unroll
  for (int p = 0; p < 16; ++p) {
    int r = p * 4 + r0;
    WT[(o0 + r) * 768 + i0 + c] = T[c][r];
  }
}

// ------------------------------------------------------------------- GEMMs --
#define LDPG 72  // BK=64 + 8 pad

// Fragment-order layouts (per bh = b*12+h, per 128-key tile kt):
//  K: elem(key,d) -> kt*8192 + ((nk*2+kk)*64 + quad*16 + l15)*8 + j
//     nk=key128>>4, l15=key128&15, kk=d>>5, quad=(d>>3)&3, j=d&7
//  V: elem(key,d) -> kt*8192 + ((nk*4+nd)*64 + vq*16 + vl15)*4 + j
//     nk=key128>>4, vq=(key128>>2)&3, j=key128&3, nd=d>>4, vl15=d&15

// Fused QKV, M = output channels (768), N = tokens (4096).
__global__ __launch_bounds__(256) void gemm_qkv(
    const bf16_t* __restrict__ Xb, const bf16_t* __restrict__ WqT,
    const bf16_t* __restrict__ WkT, const bf16_t* __restrict__ WvT,
    const float* __restrict__ bq, const float* __restrict__ bk,
    const float* __restrict__ bv, bf16_t* __restrict__ qw,
    bf16_t* __restrict__ kw, bf16_t* __restrict__ vtw) {
  __shared__ bf16_t Al[128 * LDPG];
  __shared__ bf16_t Bl[128 * LDPG];
  const int z = blockIdx.z;
  const bf16_t* Wt = (z == 0) ? WqT : (z == 1) ? WkT : WvT;
  const float* bias = (z == 0) ? bq : (z == 1) ? bk : bv;
  const float oscale = (z == 0) ? 0.18033688011112042f : 1.0f;  // 0.125*log2(e)

  const int tid = threadIdx.x, lane = tid & 63, w = tid >> 6;
  const int wr = w >> 1, wc = w & 1;
  const int l15 = lane & 15, quad = lane >> 4;
  const int m0 = blockIdx.y * 128, n0 = blockIdx.x * 128;

  floatx4 acc[4][4] = {};

  for (int kt = 0; kt < 768; kt += 64) {
#pragma unroll
    for (int p = 0; p < 4; ++p) {
      int c = p * 256 + tid;
      int row = c >> 3, qo = (c & 7) * 8;
      *(bf16x8*)&Al[row * LDPG + qo] = *(const bf16x8*)&Wt[(m0 + row) * 768 + kt + qo];
      *(bf16x8*)&Bl[row * LDPG + qo] = *(const bf16x8*)&Xb[(n0 + row) * 768 + kt + qo];
    }
    __syncthreads();
#pragma unroll
    for (int kk = 0; kk < 2; ++kk) {
      bf16x8 af[4], bfr[4];
#pragma unroll
      for (int i = 0; i < 4; ++i) {
        af[i]  = *(bf16x8*)&Al[(wr * 64 + i * 16 + l15) * LDPG + kk * 32 + quad * 8];
        bfr[i] = *(bf16x8*)&Bl[(wc * 64 + i * 16 + l15) * LDPG + kk * 32 + quad * 8];
      }
#pragma unroll
      for (int mi = 0; mi < 4; ++mi)
#pragma unroll
        for (int ni = 0; ni < 4; ++ni)
          acc[mi][ni] = MFMA32(af[mi], bfr[ni], acc[mi][ni]);
    }
    __syncthreads();
  }

  const int hh = (m0 + wr * 64) >> 6;  // head (64-aligned per wave-row)
#pragma unroll
  for (int mi = 0; mi < 4; ++mi) {
    const int d0 = mi * 16 + quad * 4;           // d within head, multiple of 4
    const int gm0 = m0 + wr * 64 + d0;
    float bv4[4];
#pragma unroll
    for (int r = 0; r < 4; ++r) bv4[r] = bias[gm0 + r];
#pragma unroll
    for (int ni = 0; ni < 4; ++ni) {
      const int gn = n0 + wc * 64 + ni * 16 + l15;
      const int bb = gn >> 11, tok = gn & 2047;
      const int bh = bb * 12 + hh;
      if (z == 0) {
        bf16x4 pk;
#pragma unroll
        for (int r = 0; r < 4; ++r)
          pk[r] = (bf16_t)((acc[mi][ni][r] + bv4[r]) * oscale);
        *(bf16x4*)&qw[bh * 131072 + tok * 64 + d0] = pk;
      } else if (z == 1) {
        const int kt2 = tok >> 7, k128 = tok & 127;
        const int nk = k128 >> 4, kl15 = k128 & 15;
        const int kk = d0 >> 5, kq = (d0 >> 3) & 3, j0 = d0 & 7;
        bf16x4 pk;
#pragma unroll
        for (int r = 0; r < 4; ++r)
          pk[r] = (bf16_t)(acc[mi][ni][r] + bv4[r]);
        *(bf16x4*)&kw[bh * 131072 + kt2 * 8192 +
                      ((nk * 2 + kk) * 64 + kq * 16 + kl15) * 8 + j0] = pk;
      } else {
        const int kt2 = tok >> 7, k128 = tok & 127;
        const int nk = k128 >> 4, vq = (k128 >> 2) & 3, j = k128 & 3;
        const int nd = d0 >> 4, vl0 = d0 & 15;
        const int base = bh * 131072 + kt2 * 8192 +
                         ((nk * 4 + nd) * 64 + vq * 16 + vl0) * 4 + j;
#pragma unroll
        for (int r = 0; r < 4; ++r)
          vtw[base + r * 4] = (bf16_t)(acc[mi][ni][r] + bv4[r]);
      }
    }
  }
}

// Output projection, M = channels: out fp32 [4096 tok][768 ch] via float4 stores.
__global__ __launch_bounds__(256) void gemm_proj(
    const bf16_t* __restrict__ Yb, const bf16_t* __restrict__ WpT,
    const float* __restrict__ bias, float* __restrict__ out) {
  __shared__ bf16_t Al[128 * LDPG];
  __shared__ bf16_t Bl[128 * LDPG];
  const int tid = threadIdx.x, lane = tid & 63, w = tid >> 6;
  const int wr = w >> 1, wc = w & 1;
  const int l15 = lane & 15, quad = lane >> 4;
  const int m0 = blockIdx.y * 128, n0 = blockIdx.x * 128;

  floatx4 acc[4][4] = {};

  for (int kt = 0; kt < 768; kt += 64) {
#pragma unroll
    for (int p = 0; p < 4; ++p) {
      int c = p * 256 + tid;
      int row = c >> 3, qo = (c & 7) * 8;
      *(bf16x8*)&Al[row * LDPG + qo] = *(const bf16x8*)&WpT[(m0 + row) * 768 + kt + qo];
      *(bf16x8*)&Bl[row * LDPG + qo] = *(const bf16x8*)&Yb[(n0 + row) * 768 + kt + qo];
    }
    __syncthreads();
#pragma unroll
    for (int kk = 0; kk < 2; ++kk) {
      bf16x8 af[4], bfr[4];
#pragma unroll
      for (int i = 0; i < 4; ++i) {
        af[i]  = *(bf16x8*)&Al[(wr * 64 + i * 16 + l15) * LDPG + kk * 32 + quad * 8];
        bfr[i] = *(bf16x8*)&Bl[(wc * 64 + i * 16 + l15) * LDPG + kk * 32 + quad * 8];
      }
#pragma unroll
      for (int mi = 0; mi < 4; ++mi)
#pragma unroll
        for (int ni = 0; ni < 4; ++ni)
          acc[mi][ni] = MFMA32(af[mi], bfr[ni], acc[mi][ni]);
    }
    __syncthreads();
  }

#pragma unroll
  for (int mi = 0; mi < 4; ++mi) {
    const int gm0 = m0 + wr * 64 + mi * 16 + quad * 4;
    floatx4 bv4;
#pragma unroll
    for (int r = 0; r < 4; ++r) bv4[r] = bias[gm0 + r];
#pragma unroll
    for (int ni = 0; ni < 4; ++ni) {
      const int gn = n0 + wc * 64 + ni * 16 + l15;
      floatx4 v = acc[mi][ni] + bv4;
      *(floatx4*)&out[gn * 768 + gm0] = v;
    }
  }
}

// --------------------------------------------------------------- attention --
// Block: one (b,h), 64 Q rows.  Wave w=(wk<<1)|wq: wq picks 32-q half, wk picks
// the 32-key half of each 64-key tile.  K/V in fragment order -> each 64-key
// subtile is a contiguous 8KB range; staging = linear global_load_lds copy
// (no VGPRs, no VALU).  Double-buffered: stage(next) overlaps compute(cur);
// one __syncthreads per tile (its vmcnt(0) drain hits loads issued a full
// compute-phase earlier).  XCD mapping: block i -> XCD i&7; XCD x owns bh in
// [3x,3x+3) (1.5MB K/V, L2-resident).  lsum on MFMA pipe (ones-trick).
__global__ __launch_bounds__(256, 4) void attn_kernel(
    const bf16_t* __restrict__ Q, const bf16_t* __restrict__ Kf,
    const bf16_t* __restrict__ Vf, bf16_t* __restrict__ Y) {
  // buf b at smem+b*8192: K [0,4096), V [4096,8192) (elements)
  __shared__ __align__(16) bf16_t smem[16384];
  __shared__ float Ls[2][2][2][16];             // [wq][wk][ni][q&15]
  float* Ox = (float*)smem;                     // exchange region (16 KB used)

  const int tid = threadIdx.x, lane = tid & 63, w = tid >> 6;
  const int wq = w & 1, wk = w >> 1;
  const int l15 = lane & 15, quad = lane >> 4;

  // XCD-aware mapping (perf-only heuristic; any mapping is correct).
  const int i = blockIdx.x;           // 0..767
  const int xcd = i & 7, j = i >> 3;  // j: 0..95
  const int bh = xcd * 3 + (j >> 5);
  const int q0 = (j & 31) * 64;

  const bf16_t* Qb = Q + bh * 131072;
  const bf16_t* Kg = Kf + bh * 131072 + tid * 8;  // per-thread staging base
  const bf16_t* Vg = Vf + bh * 131072 + tid * 8;

  // Q B-frags (x32): n=q over l15, k=dh over quad*8+j.  32 q per wave.
  bf16x8 qf[2][2];
#pragma unroll
  for (int ni = 0; ni < 2; ++ni)
#pragma unroll
    for (int kk = 0; kk < 2; ++kk)
      qf[ni][kk] = *(const bf16x8*)&Qb[(q0 + wq * 32 + ni * 16 + l15) * 64 +
                                       kk * 32 + quad * 8];

  floatx4 oacc[2][4] = {};   // [ni(q16)][nd(d16)] partial over this wave's keys
  floatx4 sacc[2] = {};      // row-sums via MFMA ones-trick
  const short4_t ones = {0x3F80, 0x3F80, 0x3F80, 0x3F80};  // bf16 1.0 x4

  // stage 64-key tile t (elements [t*4096, t*4096+4096) of K and of V) into buf b
  auto stage = [&](int b, int t) {
    const bf16_t* kg = Kg + t * 4096;
    const bf16_t* vg = Vg + t * 4096;
    bf16_t* kl = smem + b * 8192 + tid * 8;
    bf16_t* vl = smem + b * 8192 + 4096 + tid * 8;
    gload16(kg, kl);
    gload16(kg + 2048, kl + 2048);
    gload16(vg, vl);
    gload16(vg + 2048, vl + 2048);
  };

  auto compute = [&](int b) {
    const bf16_t* Kl = smem + b * 8192;
    const bf16_t* Vl = smem + b * 8192 + 4096;
    // S^T = K*Q^T for this wave's 32 keys x 32 q; P = exp2 packed to x16 A-frags.
    short4_t pk[2][2];
#pragma unroll
    for (int mt = 0; mt < 2; ++mt) {
      floatx4 s[2] = {};
#pragma unroll
      for (int kk = 0; kk < 2; ++kk) {
        bf16x8 kfr = *(const bf16x8*)&Kl[((wk * 2 + mt) * 2 + kk) * 512 + lane * 8];
#pragma unroll
        for (int ni = 0; ni < 2; ++ni)
          s[ni] = MFMA32(kfr, qf[ni][kk], s[ni]);
      }
#pragma unroll
      for (int ni = 0; ni < 2; ++ni) {
        bf16x4 ph;
#pragma unroll
        for (int r = 0; r < 4; ++r)
          ph[r] = (bf16_t)__builtin_amdgcn_exp2f(s[ni][r]);
        pk[mt][ni] = __builtin_bit_cast(short4_t, ph);
      }
    }
    // O += P*V; sacc += P*1 (row-sums on the MFMA pipe).
#pragma unroll
    for (int mt = 0; mt < 2; ++mt) {
#pragma unroll
      for (int nd = 0; nd < 4; ++nd) {
        bf16x4 vfr = *(const bf16x4*)&Vl[((wk * 2 + mt) * 4 + nd) * 256 + lane * 4];
        short4_t vs = __builtin_bit_cast(short4_t, vfr);
#pragma unroll
        for (int ni = 0; ni < 2; ++ni)
          oacc[ni][nd] = MFMA16(pk[mt][ni], vs, oacc[ni][nd]);
      }
#pragma unroll
      for (int ni = 0; ni < 2; ++ni)
        sacc[ni] = MFMA16(pk[mt][ni], ones, sacc[ni]);
    }
  };

  stage(0, 0);
  __syncthreads();                       // buf0 ready (vmcnt(0) drain + barrier)
  for (int t = 0; t < 32; t += 2) {
    stage(1, t + 1);                     // async into buf1 during compute(buf0)
    compute(0);
    __syncthreads();                     // buf1 ready; everyone done with buf0
    if (t + 2 < 32) stage(0, t + 2);     // async into buf0 during compute(buf1)
    compute(1);
    __syncthreads();                     // buf0 ready; everyone done with buf1
  }

  // sacc[ni][r] = this wave's lsum for q = ni*16 + quad*4 + r (same across l15).
  if (l15 == 0) {
#pragma unroll
    for (int ni = 0; ni < 2; ++ni)
#pragma unroll
      for (int r = 0; r < 4; ++r)
        Ls[wq][wk][ni][quad * 4 + r] = sacc[ni][r];
  }

  // Each wave writes its NON-owned d-half (fp32, b128, conflict-free),
  // then reads partner's partial for its owned half.
#pragma unroll
  for (int ni = 0; ni < 2; ++ni)
#pragma unroll
    for (int ndl = 0; ndl < 2; ++ndl) {
      const int nd = (1 - wk) * 2 + ndl;
      *(floatx4*)&Ox[((((wq * 2 + wk) * 2 + ni) * 2 + ndl) * 64 + lane) * 4] =
          oacc[ni][nd];
    }
  __syncthreads();

  const int bb = bh / 12, h = bh % 12;
#pragma unroll
  for (int ni = 0; ni < 2; ++ni) {
    float tot[4];
#pragma unroll
    for (int r = 0; r < 4; ++r)
      tot[r] = Ls[wq][0][ni][quad * 4 + r] + Ls[wq][1][ni][quad * 4 + r];
#pragma unroll
    for (int ndl = 0; ndl < 2; ++ndl) {
      const int nd = wk * 2 + ndl;
      floatx4 o = oacc[ni][nd];
      floatx4 other =
          *(floatx4*)&Ox[((((wq * 2 + (1 - wk)) * 2 + ni) * 2 + ndl) * 64 + lane) * 4];
      o += other;
#pragma unroll
      for (int r = 0; r < 4; ++r) {
        const int tok = q0 + wq * 32 + ni * 16 + quad * 4 + r;
        const int col = h * 64 + nd * 16 + l15;
        Y[(bb * 2048 + tok) * 768 + col] = (bf16_t)(o[r] / tot[r]);
      }
    }
  }
}

// ------------------------------------------------------------------ launch --
extern "C" void kernel_launch(void* const* d_in, const int* in_sizes, int n_in,
                              void* d_out, int out_size, void* d_ws, size_t ws_size,
                              hipStream_t stream) {
  const float* x  = (const float*)d_in[0];
  const float* Wq = (const float*)d_in[1];
  const float* bq = (const float*)d_in[2];
  const float* Wk = (const float*)d_in[3];
  const float* bk = (const float*)d_in[4];
  const float* Wv = (const float*)d_in[5];
  const float* bv = (const float*)d_in[6];
  const float* Wp = (const float*)d_in[7];
  const float* bp = (const float*)d_in[8];
  float* out = (float*)d_out;

  char* ws = (char*)d_ws;
  bf16_t* xb  = (bf16_t*)ws; ws += (size_t)4096 * 768 * 2;
  bf16_t* WqT = (bf16_t*)ws; ws += (size_t)768 * 768 * 2;
  bf16_t* WkT = (bf16_t*)ws; ws += (size_t)768 * 768 * 2;
  bf16_t* WvT = (bf16_t*)ws; ws += (size_t)768 * 768 * 2;
  bf16_t* WpT = (bf16_t*)ws; ws += (size_t)768 * 768 * 2;
  bf16_t* qw  = (bf16_t*)ws; ws += (size_t)24 * 2048 * 64 * 2;
  bf16_t* kw  = (bf16_t*)ws; ws += (size_t)24 * 2048 * 64 * 2;
  bf16_t* vtw = (bf16_t*)ws; ws += (size_t)24 * 2048 * 64 * 2;
  bf16_t* yw  = (bf16_t*)ws; ws += (size_t)4096 * 768 * 2;

  cvt_all_kernel<<<3648, 256, 0, stream>>>(x, Wq, Wk, Wv, Wp, xb, WqT, WkT, WvT, WpT);
  gemm_qkv<<<dim3(32, 6, 3), 256, 0, stream>>>(xb, WqT, WkT, WvT, bq, bk, bv, qw, kw, vtw);
  attn_kernel<<<768, 256, 0, stream>>>(qw, kw, vtw, yw);
  gemm_proj<<<dim3(32, 6), 256, 0, stream>>>(yw, WpT, bp, out);
}